// Round 10
// baseline (742.020 us; speedup 1.0000x reference)
//
#include <hip/hip_runtime.h>
#include <math.h>

#define NROWS 65536
#define DFULL 512
#define HHEADS 8
#define KCODES 512
#define HDIM 64
#define DELTA_S 1e-4f   // S-gap cert threshold; cert bound ~8e-6 S-space, 12x margin

// ws layout (bytes), total ~7.4MB
#define WS_LOSS  0          // double
#define WS_CNTP  64         // u32[8] pair-list counts
#define WS_CNTF  96         // u32[8] full-list counts
#define WS_HIST  128        // u32[4096] -> ends 16512
#define WS_T3    16576      // f32[4096] -> ends 32960
#define WS_BFRAG 33024      // ushort[8*32*2048] 1MB -> ends 1081600
#define WS_PROW  1081600    // u32[8][65536] 2MB
#define WS_PK    3178752    // u32[8][65536] 2MB
#define WS_FULL  5275904    // u32[8][65536] 2MB -> ends 7372800

typedef short bf16x8 __attribute__((ext_vector_type(8)));
typedef float f32x4 __attribute__((ext_vector_type(4)));

__device__ __forceinline__ unsigned short f2bf(float f) {
    unsigned u = __float_as_uint(f);
    unsigned r = (u + 0x7FFFu + ((u >> 16) & 1u)) >> 16;
    return (unsigned short)r;
}
__device__ __forceinline__ float bf2f(unsigned short b) {
    return __uint_as_float(((unsigned)b) << 16);
}

// exact XLA d-chain for one candidate k (proven bit-exact in round 5)
__device__ __forceinline__ float d_xla(const float* zr, const float* __restrict__ ck,
                                       float t1, float t3v) {
    float acc = 0.0f;
    #pragma unroll
    for (int d4 = 0; d4 < 64; d4 += 4) {
        float4 cv = *(const float4*)(ck + d4);
        acc = __fmaf_rn(zr[d4+0], cv.x, acc);
        acc = __fmaf_rn(zr[d4+1], cv.y, acc);
        acc = __fmaf_rn(zr[d4+2], cv.z, acc);
        acc = __fmaf_rn(zr[d4+3], cv.w, acc);
    }
    return __fadd_rn(__fsub_rn(t1, __fmul_rn(2.0f, acc)), t3v);
}

// ---------- prep: t3 (XLA-exact sequential f32 chain) ----------
__global__ void vq_prep_t3(const float* __restrict__ cb, float* __restrict__ t3) {
    int row = blockIdx.x * blockDim.x + threadIdx.x;
    if (row >= HHEADS * KCODES) return;
    const float* c = cb + (size_t)row * HDIM;
    float s = __fmul_rn(c[0], c[0]);
    for (int i = 1; i < 64; ++i) s = __fadd_rn(s, __fmul_rn(c[i], c[i]));
    t3[row] = s;
}

// ---------- prep: packed bf16-split B fragments ----------
// t = h(3b)|kt(5b)|khalf(1b)|pass(1b)|lane(6b), 8 ushort each.
__global__ void vq_prep_bfrag(const float* __restrict__ cb, unsigned short* __restrict__ bfrag) {
    int t = blockIdx.x * blockDim.x + threadIdx.x;  // 65536
    int lane = t & 63;
    int pass = (t >> 6) & 1;
    int khalf = (t >> 7) & 1;
    int kt = (t >> 8) & 31;
    int h = t >> 13;
    int n = lane & 15, kg = lane >> 4;
    int kcode = kt * 16 + n;
    int d0 = khalf * 32 + kg * 8;
    const float* src = cb + ((size_t)(h * KCODES + kcode)) * HDIM + d0;
    unsigned short o[8];
    #pragma unroll
    for (int j = 0; j < 8; ++j) {
        float v = src[j];
        unsigned short hi = f2bf(v);
        o[j] = (pass == 0) ? hi : f2bf(__fsub_rn(v, bf2f(hi)));
    }
    *(bf16x8*)(bfrag + (size_t)t * 8) = *(const bf16x8*)o;
}

// ---------- MFMA prefilter: top-3 S_k; certify / pair-flag / full-flag ----------
__global__ __launch_bounds__(256, 4) void vq_prefilter(
    const float* __restrict__ z_e, const unsigned short* __restrict__ bfrag,
    const float* __restrict__ t3, float* __restrict__ out_idx,
    unsigned* __restrict__ cntp, unsigned* __restrict__ cntf,
    unsigned* __restrict__ prow, unsigned* __restrict__ pk,
    unsigned* __restrict__ full) {
    __shared__ __align__(16) unsigned short sb[4][2048];  // one 4-kt phase, 16KB
    const int l = threadIdx.x & 63;
    const int wv = threadIdx.x >> 6;
    const int h = blockIdx.x & 7;
    const int rowtile = (blockIdx.x >> 3) * 4 + wv;   // 16-row tile
    const size_t rowbase = (size_t)rowtile * 16;
    const int m = l & 15, kg = l >> 4;

    // A-frags: A[m][kdim], kdim = khalf*32 + kg*8 + j
    const float* zp = z_e + (rowbase + m) * DFULL + (size_t)h * HDIM + kg * 8;
    float zv0[8], zv1[8];
    {
        float4 a0 = *(const float4*)(zp);
        float4 a1 = *(const float4*)(zp + 4);
        float4 b0 = *(const float4*)(zp + 32);
        float4 b1 = *(const float4*)(zp + 36);
        zv0[0]=a0.x; zv0[1]=a0.y; zv0[2]=a0.z; zv0[3]=a0.w;
        zv0[4]=a1.x; zv0[5]=a1.y; zv0[6]=a1.z; zv0[7]=a1.w;
        zv1[0]=b0.x; zv1[1]=b0.y; zv1[2]=b0.z; zv1[3]=b0.w;
        zv1[4]=b1.x; zv1[5]=b1.y; zv1[6]=b1.z; zv1[7]=b1.w;
    }
    bf16x8 ah0, al0, ah1, al1;
    #pragma unroll
    for (int j = 0; j < 8; ++j) {
        unsigned short hi0 = f2bf(zv0[j]);
        ah0[j] = (short)hi0;
        al0[j] = (short)f2bf(__fsub_rn(zv0[j], bf2f(hi0)));
        unsigned short hi1 = f2bf(zv1[j]);
        ah1[j] = (short)hi1;
        al1[j] = (short)f2bf(__fsub_rn(zv1[j], bf2f(hi1)));
    }

    const float* t3h = t3 + (size_t)h * KCODES;
    const unsigned short* bf_h = bfrag + (size_t)h * 32 * 2048;

    float m1[4], m2[4], m3[4];
    int k1[4], k2[4];
    #pragma unroll
    for (int j = 0; j < 4; ++j) {
        m1[j] = -INFINITY; m2[j] = -INFINITY; m3[j] = -INFINITY;
        k1[j] = 0; k2[j] = 0;
    }

    // stage regs for phase 0: wave wv owns tile kt = 4p + wv (4KB = 4 chunks)
    uint4 st[4];
    {
        const uint4* gs = (const uint4*)(bf_h + (size_t)(0 * 4 + wv) * 2048);
        #pragma unroll
        for (int c = 0; c < 4; ++c) st[c] = gs[c * 64 + l];
    }

    for (int p = 0; p < 8; ++p) {
        __syncthreads();                       // prev phase reads complete
        uint4* dst = (uint4*)sb[wv];
        #pragma unroll
        for (int c = 0; c < 4; ++c) dst[c * 64 + l] = st[c];
        if (p < 7) {
            const uint4* gs = (const uint4*)(bf_h + (size_t)((p + 1) * 4 + wv) * 2048);
            #pragma unroll
            for (int c = 0; c < 4; ++c) st[c] = gs[c * 64 + l];
        }
        __syncthreads();                       // writes visible
        #pragma unroll
        for (int q = 0; q < 4; ++q) {
            const int kt = p * 4 + q;
            const unsigned short* bp = sb[q];
            bf16x8 bh0 = *(const bf16x8*)(bp + 0 * 1024 + 0 * 512 + l * 8);
            bf16x8 bl0 = *(const bf16x8*)(bp + 0 * 1024 + 1 * 512 + l * 8);
            bf16x8 bh1 = *(const bf16x8*)(bp + 1 * 1024 + 0 * 512 + l * 8);
            bf16x8 bl1 = *(const bf16x8*)(bp + 1 * 1024 + 1 * 512 + l * 8);
            float t3v = t3h[kt * 16 + m];
            f32x4 acc;
            float ini = __fmul_rn(-0.5f, t3v);
            acc[0] = ini; acc[1] = ini; acc[2] = ini; acc[3] = ini;
            acc = __builtin_amdgcn_mfma_f32_16x16x32_bf16(ah0, bl0, acc, 0, 0, 0);
            acc = __builtin_amdgcn_mfma_f32_16x16x32_bf16(al0, bh0, acc, 0, 0, 0);
            acc = __builtin_amdgcn_mfma_f32_16x16x32_bf16(ah0, bh0, acc, 0, 0, 0);
            acc = __builtin_amdgcn_mfma_f32_16x16x32_bf16(ah1, bl1, acc, 0, 0, 0);
            acc = __builtin_amdgcn_mfma_f32_16x16x32_bf16(al1, bh1, acc, 0, 0, 0);
            acc = __builtin_amdgcn_mfma_f32_16x16x32_bf16(ah1, bh1, acc, 0, 0, 0);
            int kb = kt * 16 + m;
            #pragma unroll
            for (int j = 0; j < 4; ++j) {
                float S = acc[j];
                bool g1 = S > m1[j];
                bool g2 = S > m2[j];
                bool g3 = S > m3[j];
                m3[j] = g2 ? m2[j] : (g3 ? S : m3[j]);
                m2[j] = g1 ? m1[j] : (g2 ? S : m2[j]);
                k2[j] = g1 ? k1[j] : (g2 ? kb : k2[j]);
                m1[j] = g1 ? S : m1[j];
                k1[j] = g1 ? kb : k1[j];
            }
        }
    }

    // merge top-3 (with k1,k2) across the 16 column-lanes
    #pragma unroll
    for (int off = 1; off <= 8; off <<= 1) {
        #pragma unroll
        for (int j = 0; j < 4; ++j) {
            float p1 = __shfl_xor(m1[j], off, 64);
            float p2 = __shfl_xor(m2[j], off, 64);
            float p3 = __shfl_xor(m3[j], off, 64);
            int pk1 = __shfl_xor(k1[j], off, 64);
            int pk2 = __shfl_xor(k2[j], off, 64);
            bool g = p1 > m1[j];
            float w1 = g ? p1 : m1[j];  int kw1 = g ? pk1 : k1[j];
            float w2 = g ? p2 : m2[j];  int kw2 = g ? pk2 : k2[j];
            float w3 = g ? p3 : m3[j];
            float l1 = g ? m1[j] : p1;  int kl1 = g ? k1[j] : pk1;
            float l2 = g ? m2[j] : p2;
            bool h2 = l1 > w2;
            m1[j] = w1; k1[j] = kw1;
            m2[j] = h2 ? l1 : w2;  k2[j] = h2 ? kl1 : kw2;
            m3[j] = h2 ? fmaxf(w2, l2) : fmaxf(w3, l1);
        }
    }

    // classify + write (writer lanes: m==0, each owns rows kg*4+j)
    int np = 0, nf = 0;
    unsigned prow_[4], pk_[4], frow_[4];
    if (m == 0) {
        #pragma unroll
        for (int j = 0; j < 4; ++j) {
            unsigned row = (unsigned)(rowbase + kg * 4 + j);
            out_idx[(size_t)row * HHEADS + h] = (float)k1[j];
            if ((m1[j] - m2[j]) > DELTA_S) {
                // certified
            } else if ((m1[j] - m3[j]) > DELTA_S) {
                prow_[np] = row; pk_[np] = (unsigned)k1[j] | ((unsigned)k2[j] << 16); ++np;
            } else {
                frow_[nf] = row; ++nf;
            }
        }
    }
    // wave-aggregated enqueue: pair list
    {
        int c0 = __shfl(np, 0, 64), c1 = __shfl(np, 16, 64);
        int c2 = __shfl(np, 32, 64), c3 = __shfl(np, 48, 64);
        int tot = c0 + c1 + c2 + c3;
        unsigned base = 0;
        if (l == 0 && tot) base = atomicAdd(&cntp[h], (unsigned)tot);
        base = (unsigned)__shfl((int)base, 0, 64);
        if (m == 0 && np) {
            unsigned off = base + (kg > 0 ? c0 : 0) + (kg > 1 ? c1 : 0) + (kg > 2 ? c2 : 0);
            for (int i = 0; i < np; ++i) {
                prow[(size_t)h * NROWS + off + i] = prow_[i];
                pk[(size_t)h * NROWS + off + i] = pk_[i];
            }
        }
    }
    // wave-aggregated enqueue: full list
    {
        int c0 = __shfl(nf, 0, 64), c1 = __shfl(nf, 16, 64);
        int c2 = __shfl(nf, 32, 64), c3 = __shfl(nf, 48, 64);
        int tot = c0 + c1 + c2 + c3;
        unsigned base = 0;
        if (l == 0 && tot) base = atomicAdd(&cntf[h], (unsigned)tot);
        base = (unsigned)__shfl((int)base, 0, 64);
        if (m == 0 && nf) {
            unsigned off = base + (kg > 0 ? c0 : 0) + (kg > 1 ? c1 : 0) + (kg > 2 ? c2 : 0);
            for (int i = 0; i < nf; ++i)
                full[(size_t)h * NROWS + off + i] = frow_[i];
        }
    }
}

// ---------- pair recheck: exact XLA compare of the 2 candidates ----------
__global__ __launch_bounds__(256) void vq_pair(
    const float* __restrict__ z_e, const float* __restrict__ cb,
    const float* __restrict__ t3, const unsigned* __restrict__ cntp,
    const unsigned* __restrict__ prow, const unsigned* __restrict__ pk,
    float* __restrict__ out_idx) {
    const unsigned tid = blockIdx.x * blockDim.x + threadIdx.x;
    const unsigned stride = gridDim.x * blockDim.x;
    for (int h = 0; h < HHEADS; ++h) {
        const unsigned n = cntp[h];
        const float* cbh = cb + (size_t)h * KCODES * HDIM;
        const float* t3h = t3 + (size_t)h * KCODES;
        for (unsigned i = tid; i < n; i += stride) {
            unsigned row = prow[(size_t)h * NROWS + i];
            unsigned ks = pk[(size_t)h * NROWS + i];
            int ka = (int)(ks & 0xFFFFu), kb = (int)(ks >> 16);
            int klo = min(ka, kb), khi = max(ka, kb);
            float zr[64];
            const float* zp = z_e + (size_t)row * DFULL + (size_t)h * HDIM;
            #pragma unroll
            for (int d4 = 0; d4 < 64; d4 += 4) {
                float4 v = *(const float4*)(zp + d4);
                zr[d4+0]=v.x; zr[d4+1]=v.y; zr[d4+2]=v.z; zr[d4+3]=v.w;
            }
            float t1e = __fmul_rn(zr[0], zr[0]);
            #pragma unroll
            for (int q = 1; q < 64; ++q) t1e = __fadd_rn(t1e, __fmul_rn(zr[q], zr[q]));
            float dlo = d_xla(zr, cbh + (size_t)klo * HDIM, t1e, t3h[klo]);
            float dhi = d_xla(zr, cbh + (size_t)khi * HDIM, t1e, t3h[khi]);
            out_idx[(size_t)row * HHEADS + h] = (float)((dlo <= dhi) ? klo : khi);
        }
    }
}

// ---------- full recheck (bit-exact scan), per-head batched ----------
__global__ __launch_bounds__(64) void vq_full_rc(
    const float* __restrict__ z_e, const float* __restrict__ cb,
    const float* __restrict__ t3, const unsigned* __restrict__ cntf,
    const unsigned* __restrict__ full, float* __restrict__ out_idx) {
    const int lane = threadIdx.x;
    const int h = blockIdx.x & 7;
    const int blk = blockIdx.x >> 3;            // 0..63
    const unsigned n = cntf[h];
    const unsigned* wlh = full + (size_t)h * NROWS;
    const float* cbh = cb + (size_t)h * KCODES * HDIM;
    const float* t3h = t3 + (size_t)h * KCODES;
    for (unsigned bs = (unsigned)blk * 64; bs < n; bs += 64u * 64u) {
        unsigned ii = bs + (unsigned)lane;
        bool act = ii < n;
        int row = (int)wlh[act ? ii : (n - 1)];
        float zr[64];
        const float* zp = z_e + (size_t)row * DFULL + (size_t)h * HDIM;
        #pragma unroll
        for (int d4 = 0; d4 < 64; d4 += 4) {
            float4 v = *(const float4*)(zp + d4);
            zr[d4+0]=v.x; zr[d4+1]=v.y; zr[d4+2]=v.z; zr[d4+3]=v.w;
        }
        float t1e = __fmul_rn(zr[0], zr[0]);
        #pragma unroll
        for (int q = 1; q < 64; ++q) t1e = __fadd_rn(t1e, __fmul_rn(zr[q], zr[q]));
        float bd = INFINITY;
        int bk = 0;
        for (int k = 0; k < KCODES; ++k) {
            float dk = d_xla(zr, cbh + (size_t)k * HDIM, t1e, t3h[k]);
            if (dk < bd) { bd = dk; bk = k; }   // ascending k -> first-index ties
        }
        if (act) out_idx[(size_t)row * HHEADS + h] = (float)bk;
    }
}

// ---------- gather + losses + histogram ----------
__global__ __launch_bounds__(256) void vq_gather(
    const float* __restrict__ z_e, const float* __restrict__ cb,
    const float* __restrict__ out_idx, float* __restrict__ out,
    double* __restrict__ loss_sum, unsigned* __restrict__ hist) {
    const int lane = threadIdx.x & 63;
    const int wv = threadIdx.x >> 6;
    const int h = blockIdx.x & 7;
    const int rowblk = (blockIdx.x >> 3) * 4 + wv;
    const size_t rowbase = (size_t)rowblk * 64;

    int myidx = (int)out_idx[(rowbase + lane) * HHEADS + h];
    atomicAdd(&hist[h * KCODES + myidx], 1u);

    const float* cbh = cb + (size_t)h * KCODES * HDIM;
    double lsum = 0.0;
    for (int r = 0; r < 64; ++r) {
        int ir = __shfl(myidx, r, 64);
        float cv = cbh[(size_t)ir * HDIM + lane];
        size_t ro = (rowbase + r) * DFULL + (size_t)h * HDIM + lane;
        float ze = z_e[ro];
        float df = __fsub_rn(cv, ze);
        out[ro] = __fadd_rn(ze, df);
        lsum += (double)df * (double)df;
    }
    #pragma unroll
    for (int off = 32; off; off >>= 1) lsum += __shfl_xor(lsum, off, 64);
    if (lane == 0) atomicAdd(loss_sum, lsum);
}

// ---------- scalars + perplexity ----------
__global__ void vq_final(const unsigned* __restrict__ hist,
                         const double* __restrict__ loss_sum,
                         float* __restrict__ out) {
    const int tid = threadIdx.x;
    const int wave = tid >> 6;
    const int lane = tid & 63;
    __shared__ double perp[HHEADS];
    double e = 0.0;
    for (int k = lane; k < KCODES; k += 64) {
        double p = (double)hist[wave * KCODES + k] / (double)NROWS;
        e += p * log(p + 1e-10);
    }
    #pragma unroll
    for (int off = 32; off; off >>= 1) e += __shfl_xor(e, off, 64);
    if (lane == 0) perp[wave] = exp(-e);
    __syncthreads();
    if (tid == 0) {
        double mm = 0.0;
        #pragma unroll
        for (int i = 0; i < HHEADS; ++i) mm += perp[i];
        mm /= (double)HHEADS;
        double S = *loss_sum;
        double cl = S / ((double)NROWS * (double)DFULL);
        size_t base = (size_t)NROWS * DFULL + (size_t)NROWS * HHEADS;
        out[base + 0] = (float)cl;
        out[base + 1] = (float)(0.1 * cl);
        out[base + 2] = (float)mm;
    }
}

extern "C" void kernel_launch(void* const* d_in, const int* in_sizes, int n_in,
                              void* d_out, int out_size, void* d_ws, size_t ws_size,
                              hipStream_t stream) {
    const float* z_e = (const float*)d_in[0];
    const float* cb  = (const float*)d_in[1];
    float* out = (float*)d_out;
    float* out_idx = out + (size_t)NROWS * DFULL;
    char* ws = (char*)d_ws;
    double* loss   = (double*)(ws + WS_LOSS);
    unsigned* cntp = (unsigned*)(ws + WS_CNTP);
    unsigned* cntf = (unsigned*)(ws + WS_CNTF);
    unsigned* hist = (unsigned*)(ws + WS_HIST);
    float* t3      = (float*)(ws + WS_T3);
    unsigned short* bfrag = (unsigned short*)(ws + WS_BFRAG);
    unsigned* prow = (unsigned*)(ws + WS_PROW);
    unsigned* pk   = (unsigned*)(ws + WS_PK);
    unsigned* full = (unsigned*)(ws + WS_FULL);

    // zero loss + counts + histogram
    hipMemsetAsync(ws, 0, WS_HIST + (size_t)HHEADS * KCODES * 4, stream);

    vq_prep_t3<<<dim3(16), dim3(256), 0, stream>>>(cb, t3);
    vq_prep_bfrag<<<dim3(256), dim3(256), 0, stream>>>(cb, bfrag);
    vq_prefilter<<<dim3(8192), dim3(256), 0, stream>>>(z_e, bfrag, t3, out_idx,
                                                       cntp, cntf, prow, pk, full);
    vq_pair<<<dim3(128), dim3(256), 0, stream>>>(z_e, cb, t3, cntp, prow, pk, out_idx);
    vq_full_rc<<<dim3(8 * 64), dim3(64), 0, stream>>>(z_e, cb, t3, cntf, full, out_idx);
    vq_gather<<<dim3(2048), dim3(256), 0, stream>>>(z_e, cb, out_idx, out, loss, hist);
    vq_final<<<dim3(1), dim3(512), 0, stream>>>(hist, loss, out);
}

// Round 11
// 488.488 us; speedup vs baseline: 1.5190x; 1.5190x over previous
//
#include <hip/hip_runtime.h>
#include <math.h>

#define NROWS 65536
#define DFULL 512
#define HHEADS 8
#define KCODES 512
#define HDIM 64
#define DELTA_S 1e-4f   // S-space cert threshold; cert bound ~8.5e-6, 12x margin

// ws layout (bytes)
#define WS_LOSS  0          // double
#define WS_CNTF  64         // u32[8*16] padded counters (64B stride)
#define WS_HIST  640        // u32[4096] -> ends 17024
#define WS_T3    17088      // f32[4096] -> ends 33472
#define WS_BFRAG 33536      // ushort[8*32*2048] 1MB -> ends 1082112
#define WS_FULL  1082112    // u32[8][65536] 2MB -> ends 3179264

typedef short bf16x8 __attribute__((ext_vector_type(8)));
typedef float f32x4 __attribute__((ext_vector_type(4)));

__device__ __forceinline__ unsigned short f2bf(float f) {
    unsigned u = __float_as_uint(f);
    unsigned r = (u + 0x7FFFu + ((u >> 16) & 1u)) >> 16;
    return (unsigned short)r;
}
__device__ __forceinline__ float bf2f(unsigned short b) {
    return __uint_as_float(((unsigned)b) << 16);
}

// exact XLA d-chain (bit-exact, proven round 5)
__device__ __forceinline__ float d_xla(const float* zr, const float* __restrict__ ck,
                                       float t1, float t3v) {
    float acc = 0.0f;
    #pragma unroll
    for (int d4 = 0; d4 < 64; d4 += 4) {
        float4 cv = *(const float4*)(ck + d4);
        acc = __fmaf_rn(zr[d4+0], cv.x, acc);
        acc = __fmaf_rn(zr[d4+1], cv.y, acc);
        acc = __fmaf_rn(zr[d4+2], cv.z, acc);
        acc = __fmaf_rn(zr[d4+3], cv.w, acc);
    }
    return __fadd_rn(__fsub_rn(t1, __fmul_rn(2.0f, acc)), t3v);
}

__global__ void vq_prep_t3(const float* __restrict__ cb, float* __restrict__ t3) {
    int row = blockIdx.x * blockDim.x + threadIdx.x;
    if (row >= HHEADS * KCODES) return;
    const float* c = cb + (size_t)row * HDIM;
    float s = __fmul_rn(c[0], c[0]);
    for (int i = 1; i < 64; ++i) s = __fadd_rn(s, __fmul_rn(c[i], c[i]));
    t3[row] = s;
}

// t = h(3b)|kt(5b)|khalf(1b)|pass(1b)|lane(6b), 8 ushort each.
__global__ void vq_prep_bfrag(const float* __restrict__ cb, unsigned short* __restrict__ bfrag) {
    int t = blockIdx.x * blockDim.x + threadIdx.x;  // 65536
    int lane = t & 63;
    int pass = (t >> 6) & 1;
    int khalf = (t >> 7) & 1;
    int kt = (t >> 8) & 31;
    int h = t >> 13;
    int n = lane & 15, kg = lane >> 4;
    int kcode = kt * 16 + n;
    int d0 = khalf * 32 + kg * 8;
    const float* src = cb + ((size_t)(h * KCODES + kcode)) * HDIM + d0;
    unsigned short o[8];
    #pragma unroll
    for (int j = 0; j < 8; ++j) {
        float v = src[j];
        unsigned short hi = f2bf(v);
        o[j] = (pass == 0) ? hi : f2bf(__fsub_rn(v, bf2f(hi)));
    }
    *(bf16x8*)(bfrag + (size_t)t * 8) = *(const bf16x8*)o;
}

// ---------- MFMA prefilter: 64 rows/wave (4 tiles), top-2, certify or flag ----------
__global__ __launch_bounds__(256) void vq_prefilter(
    const float* __restrict__ z_e, const unsigned short* __restrict__ bfrag,
    const float* __restrict__ t3, float* __restrict__ out_idx,
    unsigned* __restrict__ cntf, unsigned* __restrict__ full) {
    const int l = threadIdx.x & 63;
    const int wv = threadIdx.x >> 6;
    const int h = blockIdx.x & 7;
    const int wg = (blockIdx.x >> 3) * 4 + wv;   // 0..1023, 64-row group
    const size_t rowbase = (size_t)wg * 64;
    const int m = l & 15, kg = l >> 4;

    // A-frags for 4 tiles: lane = row (t*16+m), kdim = khalf*32 + kg*8 + j
    bf16x8 Ah0[4], Al0[4], Ah1[4], Al1[4];
    #pragma unroll
    for (int t = 0; t < 4; ++t) {
        const float* zp = z_e + (rowbase + t * 16 + m) * DFULL + (size_t)h * HDIM + kg * 8;
        float4 a0 = *(const float4*)(zp);
        float4 a1 = *(const float4*)(zp + 4);
        float4 b0 = *(const float4*)(zp + 32);
        float4 b1 = *(const float4*)(zp + 36);
        float zv0[8] = {a0.x, a0.y, a0.z, a0.w, a1.x, a1.y, a1.z, a1.w};
        float zv1[8] = {b0.x, b0.y, b0.z, b0.w, b1.x, b1.y, b1.z, b1.w};
        #pragma unroll
        for (int j = 0; j < 8; ++j) {
            unsigned short hi0 = f2bf(zv0[j]);
            Ah0[t][j] = (short)hi0;
            Al0[t][j] = (short)f2bf(__fsub_rn(zv0[j], bf2f(hi0)));
            unsigned short hi1 = f2bf(zv1[j]);
            Ah1[t][j] = (short)hi1;
            Al1[t][j] = (short)f2bf(__fsub_rn(zv1[j], bf2f(hi1)));
        }
    }

    const float* t3h = t3 + (size_t)h * KCODES;
    const unsigned short* bf_h = bfrag + (size_t)h * 32 * 2048;

    float m1[16], m2[16];
    int k1[16];
    #pragma unroll
    for (int s = 0; s < 16; ++s) { m1[s] = -INFINITY; m2[s] = -INFINITY; k1[s] = 0; }

    #pragma unroll 2
    for (int kt = 0; kt < 32; ++kt) {
        const unsigned short* bp = bf_h + (size_t)kt * 2048;
        bf16x8 bh0 = *(const bf16x8*)(bp + l * 8);
        bf16x8 bl0 = *(const bf16x8*)(bp + 512 + l * 8);
        bf16x8 bh1 = *(const bf16x8*)(bp + 1024 + l * 8);
        bf16x8 bl1 = *(const bf16x8*)(bp + 1536 + l * 8);
        float nht = __fmul_rn(-0.5f, t3h[kt * 16 + m]);
        int kb = kt * 16 + m;
        #pragma unroll
        for (int t = 0; t < 4; ++t) {
            f32x4 acc;
            acc[0] = nht; acc[1] = nht; acc[2] = nht; acc[3] = nht;
            acc = __builtin_amdgcn_mfma_f32_16x16x32_bf16(Ah0[t], bl0, acc, 0, 0, 0);
            acc = __builtin_amdgcn_mfma_f32_16x16x32_bf16(Al0[t], bh0, acc, 0, 0, 0);
            acc = __builtin_amdgcn_mfma_f32_16x16x32_bf16(Ah0[t], bh0, acc, 0, 0, 0);
            acc = __builtin_amdgcn_mfma_f32_16x16x32_bf16(Ah1[t], bl1, acc, 0, 0, 0);
            acc = __builtin_amdgcn_mfma_f32_16x16x32_bf16(Al1[t], bh1, acc, 0, 0, 0);
            acc = __builtin_amdgcn_mfma_f32_16x16x32_bf16(Ah1[t], bh1, acc, 0, 0, 0);
            #pragma unroll
            for (int j = 0; j < 4; ++j) {
                const int s = t * 4 + j;
                float S = acc[j];
                float m1o = m1[s];
                m2[s] = fmaxf(m2[s], fminf(S, m1o));   // branchless 2nd-max
                k1[s] = (S > m1o) ? kb : k1[s];
                m1[s] = fmaxf(m1o, S);
            }
        }
    }

    // merge top-2 across the 16 column-lanes (codes within ktile)
    #pragma unroll
    for (int off = 1; off <= 8; off <<= 1) {
        #pragma unroll
        for (int s = 0; s < 16; ++s) {
            float p1 = __shfl_xor(m1[s], off, 64);
            float p2 = __shfl_xor(m2[s], off, 64);
            int pk = __shfl_xor(k1[s], off, 64);
            float nm2 = fmaxf(fminf(m1[s], p1), fmaxf(m2[s], p2));
            bool g = p1 > m1[s];
            k1[s] = g ? pk : k1[s];
            m1[s] = g ? p1 : m1[s];
            m2[s] = nm2;
        }
    }
    // ties (m1==m2 across lanes) are never certified -> exact recheck resolves
    // first-index semantics; certified rows have a unique >delta winner.

    unsigned mask = 0;
    if (m == 0) {
        #pragma unroll
        for (int t = 0; t < 4; ++t) {
            #pragma unroll
            for (int j = 0; j < 4; ++j) {
                const int s = t * 4 + j;
                size_t row = rowbase + t * 16 + kg * 4 + j;   // C/D row=(l>>4)*4+j
                out_idx[row * HHEADS + h] = (float)k1[s];
                if (!((m1[s] - m2[s]) > DELTA_S)) mask |= (1u << s);
            }
        }
    }
    int nf = __popc(mask);
    int c0 = __shfl(nf, 0, 64), c1 = __shfl(nf, 16, 64);
    int c2 = __shfl(nf, 32, 64), c3 = __shfl(nf, 48, 64);
    int tot = c0 + c1 + c2 + c3;
    unsigned base = 0;
    if (l == 0 && tot) base = atomicAdd(&cntf[h * 16], (unsigned)tot);
    base = (unsigned)__shfl((int)base, 0, 64);
    if (m == 0 && mask) {
        unsigned off = base + (kg > 0 ? c0 : 0) + (kg > 1 ? c1 : 0) + (kg > 2 ? c2 : 0);
        while (mask) {
            int s = __builtin_ctz(mask);
            mask &= mask - 1;
            unsigned row = (unsigned)rowbase + (unsigned)((s >> 2) * 16 + kg * 4 + (s & 3));
            full[(size_t)h * NROWS + off++] = row;
        }
    }
}

// ---------- exact recheck (bit-exact XLA scan), per-head batched ----------
__global__ __launch_bounds__(64) void vq_full_rc(
    const float* __restrict__ z_e, const float* __restrict__ cb,
    const float* __restrict__ t3, const unsigned* __restrict__ cntf,
    const unsigned* __restrict__ full, float* __restrict__ out_idx) {
    const int lane = threadIdx.x;
    const int h = blockIdx.x & 7;
    const int blk = blockIdx.x >> 3;            // 0..255
    const unsigned n = cntf[h * 16];
    const unsigned* wlh = full + (size_t)h * NROWS;
    const float* cbh = cb + (size_t)h * KCODES * HDIM;
    const float* t3h = t3 + (size_t)h * KCODES;
    for (unsigned bs = (unsigned)blk * 64; bs < n; bs += 256u * 64u) {
        unsigned ii = bs + (unsigned)lane;
        bool act = ii < n;
        int row = (int)wlh[act ? ii : (n - 1)];
        float zr[64];
        const float* zp = z_e + (size_t)row * DFULL + (size_t)h * HDIM;
        #pragma unroll
        for (int d4 = 0; d4 < 64; d4 += 4) {
            float4 v = *(const float4*)(zp + d4);
            zr[d4+0]=v.x; zr[d4+1]=v.y; zr[d4+2]=v.z; zr[d4+3]=v.w;
        }
        float t1e = __fmul_rn(zr[0], zr[0]);
        #pragma unroll
        for (int q = 1; q < 64; ++q) t1e = __fadd_rn(t1e, __fmul_rn(zr[q], zr[q]));
        float bd = INFINITY;
        int bk = 0;
        for (int k = 0; k < KCODES; ++k) {
            float dk = d_xla(zr, cbh + (size_t)k * HDIM, t1e, t3h[k]);
            if (dk < bd) { bd = dk; bk = k; }   // ascending k -> first-index ties
        }
        if (act) out_idx[(size_t)row * HHEADS + h] = (float)bk;
    }
}

// ---------- gather + losses + histogram ----------
__global__ __launch_bounds__(256) void vq_gather(
    const float* __restrict__ z_e, const float* __restrict__ cb,
    const float* __restrict__ out_idx, float* __restrict__ out,
    double* __restrict__ loss_sum, unsigned* __restrict__ hist) {
    const int lane = threadIdx.x & 63;
    const int wv = threadIdx.x >> 6;
    const int h = blockIdx.x & 7;
    const int rowblk = (blockIdx.x >> 3) * 4 + wv;
    const size_t rowbase = (size_t)rowblk * 64;

    int myidx = (int)out_idx[(rowbase + lane) * HHEADS + h];
    atomicAdd(&hist[h * KCODES + myidx], 1u);

    const float* cbh = cb + (size_t)h * KCODES * HDIM;
    double lsum = 0.0;
    #pragma unroll 4
    for (int r = 0; r < 64; ++r) {
        int ir = __shfl(myidx, r, 64);
        float cv = cbh[(size_t)ir * HDIM + lane];
        size_t ro = (rowbase + r) * DFULL + (size_t)h * HDIM + lane;
        float ze = z_e[ro];
        float df = __fsub_rn(cv, ze);
        out[ro] = __fadd_rn(ze, df);
        lsum += (double)df * (double)df;
    }
    #pragma unroll
    for (int off = 32; off; off >>= 1) lsum += __shfl_xor(lsum, off, 64);
    if (lane == 0) atomicAdd(loss_sum, lsum);
}

__global__ void vq_final(const unsigned* __restrict__ hist,
                         const double* __restrict__ loss_sum,
                         float* __restrict__ out) {
    const int tid = threadIdx.x;
    const int wave = tid >> 6;
    const int lane = tid & 63;
    __shared__ double perp[HHEADS];
    double e = 0.0;
    for (int k = lane; k < KCODES; k += 64) {
        double p = (double)hist[wave * KCODES + k] / (double)NROWS;
        e += p * log(p + 1e-10);
    }
    #pragma unroll
    for (int off = 32; off; off >>= 1) e += __shfl_xor(e, off, 64);
    if (lane == 0) perp[wave] = exp(-e);
    __syncthreads();
    if (tid == 0) {
        double mm = 0.0;
        #pragma unroll
        for (int i = 0; i < HHEADS; ++i) mm += perp[i];
        mm /= (double)HHEADS;
        double S = *loss_sum;
        double cl = S / ((double)NROWS * (double)DFULL);
        size_t base = (size_t)NROWS * DFULL + (size_t)NROWS * HHEADS;
        out[base + 0] = (float)cl;
        out[base + 1] = (float)(0.1 * cl);
        out[base + 2] = (float)mm;
    }
}

extern "C" void kernel_launch(void* const* d_in, const int* in_sizes, int n_in,
                              void* d_out, int out_size, void* d_ws, size_t ws_size,
                              hipStream_t stream) {
    const float* z_e = (const float*)d_in[0];
    const float* cb  = (const float*)d_in[1];
    float* out = (float*)d_out;
    float* out_idx = out + (size_t)NROWS * DFULL;
    char* ws = (char*)d_ws;
    double* loss   = (double*)(ws + WS_LOSS);
    unsigned* cntf = (unsigned*)(ws + WS_CNTF);
    unsigned* hist = (unsigned*)(ws + WS_HIST);
    float* t3      = (float*)(ws + WS_T3);
    unsigned short* bfrag = (unsigned short*)(ws + WS_BFRAG);
    unsigned* full = (unsigned*)(ws + WS_FULL);

    // zero loss + padded counters + histogram
    hipMemsetAsync(ws, 0, WS_HIST + (size_t)HHEADS * KCODES * 4, stream);

    vq_prep_t3<<<dim3(16), dim3(256), 0, stream>>>(cb, t3);
    vq_prep_bfrag<<<dim3(256), dim3(256), 0, stream>>>(cb, bfrag);
    vq_prefilter<<<dim3(2048), dim3(256), 0, stream>>>(z_e, bfrag, t3, out_idx, cntf, full);
    vq_full_rc<<<dim3(8 * 256), dim3(64), 0, stream>>>(z_e, cb, t3, cntf, full, out_idx);
    vq_gather<<<dim3(2048), dim3(256), 0, stream>>>(z_e, cb, out_idx, out, loss, hist);
    vq_final<<<dim3(1), dim3(512), 0, stream>>>(hist, loss, out);
}